// Round 7
// baseline (235.100 us; speedup 1.0000x reference)
//
#include <hip/hip_runtime.h>
#include <hip/hip_bf16.h>
#include <math.h>

#define B_ROWS 16384
#define C_COLS 1000
#define C_PAD  1024
#define FDIM   1024
#define FBLKS  4096           // feature normalize blocks (4 rows each)
#define FP8_SCALE 256.0f      // pre-scale before e4m3 quant (avoids subnormals)
#define INV_SIM   (1.0f / (FP8_SCALE * FP8_SCALE))

typedef __attribute__((ext_vector_type(8))) short bf16x8;
typedef __attribute__((ext_vector_type(4))) float f32x4;
typedef __attribute__((ext_vector_type(4))) int   i32x4;
typedef __attribute__((ext_vector_type(8))) int   i32x8;

// async global->LDS, 16B per lane; lds dst is wave-uniform base (HW puts lane i at base + i*16)
#define GLD_LDS(gp, lp) __builtin_amdgcn_global_load_lds( \
    (__attribute__((address_space(1))) void*)(gp),        \
    (__attribute__((address_space(3))) void*)(lp), 16, 0, 0)

// ---------------- fused row L2-normalize fp32 -> fp8 e4m3 (x256), one wave per row ---------
__global__ __launch_bounds__(256) void normalize_all(
    const float* __restrict__ feat, const float* __restrict__ prot,
    unsigned char* __restrict__ fb, unsigned char* __restrict__ pb,
    float* __restrict__ rowsum, unsigned int* __restrict__ cnt)
{
    const int lane = threadIdx.x & 63;
    const int wave = threadIdx.x >> 6;

    // fold rowsum + last-arriver-counter zeroing into the first blocks (replaces memsets)
    if (blockIdx.x < 64) rowsum[blockIdx.x * 256 + threadIdx.x] = 0.0f;
    if (blockIdx.x == 64 && threadIdx.x < 128) cnt[threadIdx.x] = 0u;

    const float* in;
    unsigned char* out;
    int row, nvalid;
    if (blockIdx.x < FBLKS) {
        row = blockIdx.x * 4 + wave;  in = feat; out = fb; nvalid = B_ROWS;
    } else {
        row = (blockIdx.x - FBLKS) * 4 + wave;  in = prot; out = pb; nvalid = C_COLS;
    }
    unsigned char* orow = out + (size_t)row * FDIM;

    if (row >= nvalid) {               // zero-pad prototype rows 1000..1023
        i32x4 z = {0, 0, 0, 0};
        ((i32x4*)orow)[lane] = z;      // 64 lanes x 16 B = 1024 B row
        return;
    }

    // lane owns 16 contiguous elements -> one 16 B fp8 store
    const float4* rp = (const float4*)(in + (size_t)row * FDIM);
    float4 v[4];
    float ss = 0.0f;
    #pragma unroll
    for (int c = 0; c < 4; ++c) {
        v[c] = rp[lane * 4 + c];
        ss += v[c].x * v[c].x + v[c].y * v[c].y + v[c].z * v[c].z + v[c].w * v[c].w;
    }
    #pragma unroll
    for (int off = 1; off < 64; off <<= 1) ss += __shfl_xor(ss, off, 64);
    const float inv = FP8_SCALE / sqrtf(fmaxf(ss, 1e-24f));

    i32x4 pk;
    #pragma unroll
    for (int c = 0; c < 4; ++c) {
        int w0 = __builtin_amdgcn_cvt_pk_fp8_f32(v[c].x * inv, v[c].y * inv, 0, false);
        w0     = __builtin_amdgcn_cvt_pk_fp8_f32(v[c].z * inv, v[c].w * inv, w0, true);
        pk[c] = w0;
    }
    ((i32x4*)orow)[lane] = pk;
}

// ---------------- MX-fp8 GEMM 128x128 (counted-vmcnt depth-2 pipeline, r6 core, unchanged)
// + last-arriver fused finalize: the 8th bn-block of each bm slab converts D->out for the
// whole 128x1000 slab (device-scope ACQ_REL counter; no co-residency assumption).
__global__ __launch_bounds__(256) void gemm_dist(
    const unsigned char* __restrict__ A,
    const unsigned char* __restrict__ Bp,
    __hip_bfloat16* __restrict__ D,
    float* __restrict__ rowsum,
    unsigned int* __restrict__ cnt,
    const float* __restrict__ scale,
    const float* __restrict__ temp,
    float* __restrict__ out)
{
    __shared__ unsigned char As[2 * 128 * 128];   // 32 KB (double-buffered)
    __shared__ unsigned char Bs[2 * 128 * 128];   // 32 KB
    __shared__ int last_flag;

    const int tid  = threadIdx.x;
    const int lane = tid & 63;
    const int wave = tid >> 6;

    // XCD swizzle: the 8 bn-blocks of one bm share id%8 (same XCD) for A-tile L2 reuse
    const int id  = blockIdx.x;             // 0..1023
    const int xcd = id & 7;
    const int seq = id >> 3;                // 0..127
    const int bn  = seq & 7;                // 0..7
    const int bm  = xcd * 16 + (seq >> 3);  // 0..127

    const int waveM = (wave >> 1) * 64;
    const int waveN = (wave & 1) * 64;

    f32x4 acc[4][4] = {};

    // staging: round r covers rows [r*32, r*32+32); wave w -> rows r*32+w*8 .. +8
    // lane i -> row +(i>>3), phys granule i&7, fetching logical granule (i&7)^(i>>3)
    const int srow8 = lane >> 3;
    const int sg    = (lane & 7) ^ srow8;
    const unsigned char* Abase = A  + ((size_t)(bm * 128 + wave * 8 + srow8)) * FDIM + sg * 16;
    const unsigned char* Bbase = Bp + ((size_t)(bn * 128 + wave * 8 + srow8)) * FDIM + sg * 16;

    // frag addressing: R = waveX + mt*16 + (lane&15); R&7 = lane&7.
    // logical granules for this lane: 2q, 2q+1 (q = lane>>4); phys = g ^ (lane&7)
    const int q2   = (lane >> 4) * 2;
    const int bxor = lane & 7;
    const int fA = (waveM + (lane & 15)) * 128;
    const int fB = (waveN + (lane & 15)) * 128;
    const int pg0 = ((q2)     ^ bxor) * 16;
    const int pg1 = ((q2 + 1) ^ bxor) * 16;

    const int ldsRow = wave * 8 * 128;      // this wave's staging base within a tile

    // prologue: batch0 -> buf0, batch1 -> buf1 (issue order = vmcnt retirement order)
    #pragma unroll
    for (int r = 0; r < 4; ++r) {
        GLD_LDS(Abase + (size_t)(r * 32) * FDIM, &As[ldsRow + r * 32 * 128]);
        GLD_LDS(Bbase + (size_t)(r * 32) * FDIM, &Bs[ldsRow + r * 32 * 128]);
    }
    __builtin_amdgcn_sched_barrier(0);
    #pragma unroll
    for (int r = 0; r < 4; ++r) {
        GLD_LDS(Abase + (size_t)(r * 32) * FDIM + 128, &As[16384 + ldsRow + r * 32 * 128]);
        GLD_LDS(Bbase + (size_t)(r * 32) * FDIM + 128, &Bs[16384 + ldsRow + r * 32 * 128]);
    }
    __builtin_amdgcn_sched_barrier(0);

    #pragma unroll 1
    for (int t = 0; t < 7; ++t) {
        // own batch-t retired (8 newest = later batches still in flight), then
        // barrier => ALL waves' batch-t slices landed in buf[t&1]
        asm volatile("s_waitcnt vmcnt(8)" ::: "memory");
        __builtin_amdgcn_s_barrier();
        __builtin_amdgcn_sched_barrier(0);

        const int cur = (t & 1) << 14;      // byte offset of current buffer (0 / 16384)

        i32x8 a4[4], b4[4];
        #pragma unroll
        for (int nt = 0; nt < 4; ++nt) {
            const i32x4 lo = *(const i32x4*)&Bs[cur + fB + nt * 2048 + pg0];
            const i32x4 hi = *(const i32x4*)&Bs[cur + fB + nt * 2048 + pg1];
            b4[nt] = (i32x8){lo.x, lo.y, lo.z, lo.w, hi.x, hi.y, hi.z, hi.w};
        }
        #pragma unroll
        for (int mt = 0; mt < 4; ++mt) {
            const i32x4 lo = *(const i32x4*)&As[cur + fA + mt * 2048 + pg0];
            const i32x4 hi = *(const i32x4*)&As[cur + fA + mt * 2048 + pg1];
            a4[mt] = (i32x8){lo.x, lo.y, lo.z, lo.w, hi.x, hi.y, hi.z, hi.w};
        }

        __builtin_amdgcn_s_setprio(1);
        #pragma unroll
        for (int mt = 0; mt < 4; ++mt)
            #pragma unroll
            for (int nt = 0; nt < 4; ++nt)
                acc[mt][nt] = __builtin_amdgcn_mfma_scale_f32_16x16x128_f8f6f4(
                    a4[mt], b4[nt], acc[mt][nt], 0, 0, 0, 127, 0, 127);
        __builtin_amdgcn_s_setprio(0);

        if (t < 6) {
            // all waves done READING buf[cur], then overwrite it with batch t+2;
            // loads stay in flight across the next barrier (counted vmcnt)
            asm volatile("s_waitcnt lgkmcnt(0)" ::: "memory");
            __builtin_amdgcn_s_barrier();
            __builtin_amdgcn_sched_barrier(0);
            const int k0n = (t + 2) * 128;
            #pragma unroll
            for (int r = 0; r < 4; ++r) {
                GLD_LDS(Abase + (size_t)(r * 32) * FDIM + k0n, &As[cur + ldsRow + r * 32 * 128]);
                GLD_LDS(Bbase + (size_t)(r * 32) * FDIM + k0n, &Bs[cur + ldsRow + r * 32 * 128]);
            }
            __builtin_amdgcn_sched_barrier(0);
        }
    }

    // peeled last K-step (t=7): buf1, full drain
    asm volatile("s_waitcnt vmcnt(0)" ::: "memory");
    __builtin_amdgcn_s_barrier();
    __builtin_amdgcn_sched_barrier(0);
    {
        const int cur = 16384;
        i32x8 a4[4], b4[4];
        #pragma unroll
        for (int nt = 0; nt < 4; ++nt) {
            const i32x4 lo = *(const i32x4*)&Bs[cur + fB + nt * 2048 + pg0];
            const i32x4 hi = *(const i32x4*)&Bs[cur + fB + nt * 2048 + pg1];
            b4[nt] = (i32x8){lo.x, lo.y, lo.z, lo.w, hi.x, hi.y, hi.z, hi.w};
        }
        #pragma unroll
        for (int mt = 0; mt < 4; ++mt) {
            const i32x4 lo = *(const i32x4*)&As[cur + fA + mt * 2048 + pg0];
            const i32x4 hi = *(const i32x4*)&As[cur + fA + mt * 2048 + pg1];
            a4[mt] = (i32x8){lo.x, lo.y, lo.z, lo.w, hi.x, hi.y, hi.z, hi.w};
        }
        __builtin_amdgcn_s_setprio(1);
        #pragma unroll
        for (int mt = 0; mt < 4; ++mt)
            #pragma unroll
            for (int nt = 0; nt < 4; ++nt)
                acc[mt][nt] = __builtin_amdgcn_mfma_scale_f32_16x16x128_f8f6f4(
                    a4[mt], b4[nt], acc[mt][nt], 0, 0, 0, 127, 0, 127);
        __builtin_amdgcn_s_setprio(0);
    }

    // epilogue: sim = acc/65536; d = sqrt(max(1-sim,0)); C/D: col=lane&15, row=(lane>>4)*4+reg
    const int row0 = bm * 128 + waveM;
    const int col0 = bn * 128 + waveN;
    #pragma unroll
    for (int mt = 0; mt < 4; ++mt) {
        #pragma unroll
        for (int r = 0; r < 4; ++r) {
            const int row = row0 + mt * 16 + (lane >> 4) * 4 + r;
            float part = 0.0f;
            #pragma unroll
            for (int nt = 0; nt < 4; ++nt) {
                const int col = col0 + nt * 16 + (lane & 15);
                const float sim = acc[mt][nt][r] * INV_SIM;
                const float dv = sqrtf(fmaxf(1.0f - sim, 0.0f));
                if (col < C_COLS) {
                    D[(size_t)row * C_COLS + col] = __float2bfloat16(dv);
                    part += dv;
                }
            }
            part += __shfl_xor(part, 1, 64);
            part += __shfl_xor(part, 2, 64);
            part += __shfl_xor(part, 4, 64);
            part += __shfl_xor(part, 8, 64);
            if ((lane & 15) == 0) atomicAdd(&rowsum[row], part);
        }
    }

    // ---- last-arriver fused finalize for this bm slab (128 rows x 1000 cols) ----
    // __syncthreads(): every wave's D stores + rowsum atomics retired (per-wave vmcnt(0)
    // before s_barrier). ACQ_REL agent-scope counter = device-wide sync point: the 8th
    // arriver's cold reads of other blocks' D/rowsum see the released values.
    __syncthreads();
    if (tid == 0) {
        unsigned int old = __hip_atomic_fetch_add(&cnt[bm], 1u,
                                                  __ATOMIC_ACQ_REL, __HIP_MEMORY_SCOPE_AGENT);
        last_flag = (old == 7u);
    }
    __syncthreads();

    if (last_flag) {
        const float aS = -fabsf(scale[0]) / temp[0];
        const int rbase = bm * 128;
        // slab = 128 rows x 1000 cols = 16000 groups of 8 (1000 % 8 == 0, no straddle)
        for (int g = tid; g < 16000; g += 256) {
            const int rloc = g / 125;                 // 125 groups per row
            const int row  = rbase + rloc;
            const float m = __hip_atomic_load(&rowsum[row], __ATOMIC_RELAXED,
                                              __HIP_MEMORY_SCOPE_AGENT) * (1.0f / (float)C_COLS);
            const size_t idx = (size_t)row * C_COLS + (g - rloc * 125) * 8;
            const bf16x8 dv = *(const bf16x8*)(D + idx);
            const __hip_bfloat16* dp = (const __hip_bfloat16*)&dv;
            float4 o0, o1;
            o0.x = aS * (__bfloat162float(dp[0]) + m);
            o0.y = aS * (__bfloat162float(dp[1]) + m);
            o0.z = aS * (__bfloat162float(dp[2]) + m);
            o0.w = aS * (__bfloat162float(dp[3]) + m);
            o1.x = aS * (__bfloat162float(dp[4]) + m);
            o1.y = aS * (__bfloat162float(dp[5]) + m);
            o1.z = aS * (__bfloat162float(dp[6]) + m);
            o1.w = aS * (__bfloat162float(dp[7]) + m);
            *(float4*)(out + idx)     = o0;
            *(float4*)(out + idx + 4) = o1;
        }
    }
}

extern "C" void kernel_launch(void* const* d_in, const int* in_sizes, int n_in,
                              void* d_out, int out_size, void* d_ws, size_t ws_size,
                              hipStream_t stream)
{
    const float* features = (const float*)d_in[0];   // [16384,1024]
    const float* protos   = (const float*)d_in[1];   // [1000,1024]
    const float* dscale   = (const float*)d_in[2];   // [1]
    const float* temp     = (const float*)d_in[3];   // [1]
    float* out = (float*)d_out;                      // [16384,1000]

    char* ws = (char*)d_ws;
    unsigned char* fb = (unsigned char*)ws;                       // 16,777,216 B
    unsigned char* pb = (unsigned char*)(ws + 16777216);          //  1,048,576 B
    __hip_bfloat16* D = (__hip_bfloat16*)(ws + 17825792);         // 32,768,000 B
    float* rowsum     = (float*)(ws + 50593792);                  //     65,536 B
    unsigned int* cnt = (unsigned int*)(ws + 50659328);           //        512 B

    normalize_all<<<FBLKS + C_PAD / 4, 256, 0, stream>>>(features, protos, fb, pb, rowsum, cnt);

    gemm_dist<<<1024, 256, 0, stream>>>(fb, pb, D, rowsum, cnt, dscale, temp, out);
}

// Round 8
// 174.827 us; speedup vs baseline: 1.3448x; 1.3448x over previous
//
#include <hip/hip_runtime.h>
#include <hip/hip_bf16.h>
#include <math.h>

#define B_ROWS 16384
#define C_COLS 1000
#define C_PAD  1024
#define FDIM   1024
#define FBLKS  4096           // feature normalize blocks (4 rows each)
#define FP8_SCALE 256.0f      // pre-scale before e4m3 quant (avoids subnormals)
#define INV_SIM   (1.0f / (FP8_SCALE * FP8_SCALE))

typedef __attribute__((ext_vector_type(8))) short bf16x8;
typedef __attribute__((ext_vector_type(4))) float f32x4;
typedef __attribute__((ext_vector_type(4))) int   i32x4;
typedef __attribute__((ext_vector_type(8))) int   i32x8;

// async global->LDS, 16B per lane; lds dst is wave-uniform base (HW puts lane i at base + i*16)
#define GLD_LDS(gp, lp) __builtin_amdgcn_global_load_lds( \
    (__attribute__((address_space(1))) void*)(gp),        \
    (__attribute__((address_space(3))) void*)(lp), 16, 0, 0)

// ---------------- fused row L2-normalize fp32 -> fp8 e4m3 (x256), one wave per row ---------
__global__ __launch_bounds__(256) void normalize_all(
    const float* __restrict__ feat, const float* __restrict__ prot,
    unsigned char* __restrict__ fb, unsigned char* __restrict__ pb,
    float* __restrict__ rowsum)
{
    const int lane = threadIdx.x & 63;
    const int wave = threadIdx.x >> 6;

    // fold rowsum zeroing into the first 64 blocks (replaces the memset dispatch)
    if (blockIdx.x < 64) rowsum[blockIdx.x * 256 + threadIdx.x] = 0.0f;

    const float* in;
    unsigned char* out;
    int row, nvalid;
    if (blockIdx.x < FBLKS) {
        row = blockIdx.x * 4 + wave;  in = feat; out = fb; nvalid = B_ROWS;
    } else {
        row = (blockIdx.x - FBLKS) * 4 + wave;  in = prot; out = pb; nvalid = C_COLS;
    }
    unsigned char* orow = out + (size_t)row * FDIM;

    if (row >= nvalid) {               // zero-pad prototype rows 1000..1023
        i32x4 z = {0, 0, 0, 0};
        ((i32x4*)orow)[lane] = z;      // 64 lanes x 16 B = 1024 B row
        return;
    }

    // lane owns 16 contiguous elements -> one 16 B fp8 store
    const float4* rp = (const float4*)(in + (size_t)row * FDIM);
    float4 v[4];
    float ss = 0.0f;
    #pragma unroll
    for (int c = 0; c < 4; ++c) {
        v[c] = rp[lane * 4 + c];
        ss += v[c].x * v[c].x + v[c].y * v[c].y + v[c].z * v[c].z + v[c].w * v[c].w;
    }
    #pragma unroll
    for (int off = 1; off < 64; off <<= 1) ss += __shfl_xor(ss, off, 64);
    const float inv = FP8_SCALE / sqrtf(fmaxf(ss, 1e-24f));

    i32x4 pk;
    #pragma unroll
    for (int c = 0; c < 4; ++c) {
        int w0 = __builtin_amdgcn_cvt_pk_fp8_f32(v[c].x * inv, v[c].y * inv, 0, false);
        w0     = __builtin_amdgcn_cvt_pk_fp8_f32(v[c].z * inv, v[c].w * inv, w0, true);
        pk[c] = w0;
    }
    ((i32x4*)orow)[lane] = pk;
}

// ---------------- MX-fp8 GEMM 128x128: A direct-from-global, B LDS dbuf, counted vmcnt ----
// Change vs r6: As LDS buffer deleted. The A fragment (row = waveM+mt*16+(lane&15),
// bytes (lane>>4)*32 + {0,16}) is loaded as two global dwordx4 per mt straight to VGPRs --
// A is L2-resident per-XCD (8-block reuse via swizzle). LDS halves to 32 KB (B dbuf only)
// -> occupancy cap moves to VGPR (~3 blocks/CU vs 2), LDS frag reads halve, staging GLDs
// halve. Counted-vmcnt (T4) now tracks only B batches: 4 GLDs each, vmcnt(4) = batch-t
// landed (batch t+1 in flight); compiler's FIFO waits cover the A register loads.
__global__ __launch_bounds__(256) void gemm_dist(
    const unsigned char* __restrict__ A,
    const unsigned char* __restrict__ Bp,
    __hip_bfloat16* __restrict__ D,
    float* __restrict__ rowsum)
{
    __shared__ unsigned char Bs[2 * 128 * 128];   // 32 KB (B double-buffered; A = direct)

    const int tid  = threadIdx.x;
    const int lane = tid & 63;
    const int wave = tid >> 6;                    // 0..3

    // XCD swizzle: the 8 bn-blocks of one bm share id%8 (same XCD) for A-tile L2 reuse
    const int id  = blockIdx.x;             // 0..1023
    const int xcd = id & 7;
    const int seq = id >> 3;                // 0..127
    const int bn  = seq & 7;                // 0..7
    const int bm  = xcd * 16 + (seq >> 3);  // 0..127

    const int waveM = (wave >> 1) * 64;
    const int waveN = (wave & 1) * 64;

    f32x4 acc[4][4] = {};

    // B staging: round r covers rows [r*32, r*32+32); wave w -> rows r*32+w*8 .. +8
    // lane i -> row +(i>>3), phys granule i&7, fetching logical granule (i&7)^(i>>3)
    const int srow8 = lane >> 3;
    const int sg    = (lane & 7) ^ srow8;
    const unsigned char* Bbase = Bp + ((size_t)(bn * 128 + wave * 8 + srow8)) * FDIM + sg * 16;

    // B frag addressing: R = waveN + nt*16 + (lane&15); R&7 = lane&7.
    // logical granules for this lane: 2q, 2q+1 (q = lane>>4); phys = g ^ (lane&7)
    const int q2   = (lane >> 4) * 2;
    const int bxor = lane & 7;
    const int fB = (waveN + (lane & 15)) * 128;
    const int pg0 = ((q2)     ^ bxor) * 16;
    const int pg1 = ((q2 + 1) ^ bxor) * 16;

    // A direct per-lane fragment base: row = bm*128 + waveM + (lane&15), byte (lane>>4)*32
    const unsigned char* Afrag =
        A + ((size_t)(bm * 128 + waveM + (lane & 15))) * FDIM + (lane >> 4) * 32;

    const int ldsRow = wave * 8 * 128;      // this wave's staging base within a tile

    // prologue: B batch0 -> buf0, batch1 -> buf1 (issue order = vmcnt retirement order)
    #pragma unroll
    for (int r = 0; r < 4; ++r)
        GLD_LDS(Bbase + (size_t)(r * 32) * FDIM, &Bs[ldsRow + r * 32 * 128]);
    __builtin_amdgcn_sched_barrier(0);
    #pragma unroll
    for (int r = 0; r < 4; ++r)
        GLD_LDS(Bbase + (size_t)(r * 32) * FDIM + 128, &Bs[16384 + ldsRow + r * 32 * 128]);
    __builtin_amdgcn_sched_barrier(0);

    #pragma unroll 1
    for (int t = 0; t < 7; ++t) {
        // B batch-t landed (4 newest = batch t+1 still in flight; older A-loads were
        // drained by the compiler's pre-MFMA vmcnt(4) last iteration), then barrier =>
        // ALL waves' batch-t slices are in buf[t&1]
        asm volatile("s_waitcnt vmcnt(4)" ::: "memory");
        __builtin_amdgcn_s_barrier();
        __builtin_amdgcn_sched_barrier(0);

        const int cur = (t & 1) << 14;      // byte offset of current B buffer (0 / 16384)
        const int k0  = t * 128;

        // A fragments: 8 global dwordx4 -> regs (L2-hot; latency hidden under ds_reads
        // and covered by the compiler's counted vmcnt before the MFMA cluster)
        i32x8 a4[4];
        #pragma unroll
        for (int mt = 0; mt < 4; ++mt) {
            const i32x4 lo = *(const i32x4*)(Afrag + (size_t)mt * 16 * FDIM + k0);
            const i32x4 hi = *(const i32x4*)(Afrag + (size_t)mt * 16 * FDIM + k0 + 16);
            a4[mt] = (i32x8){lo.x, lo.y, lo.z, lo.w, hi.x, hi.y, hi.z, hi.w};
        }

        // B fragments: 8 ds_read_b128 from buf[cur]
        i32x8 b4[4];
        #pragma unroll
        for (int nt = 0; nt < 4; ++nt) {
            const i32x4 lo = *(const i32x4*)&Bs[cur + fB + nt * 2048 + pg0];
            const i32x4 hi = *(const i32x4*)&Bs[cur + fB + nt * 2048 + pg1];
            b4[nt] = (i32x8){lo.x, lo.y, lo.z, lo.w, hi.x, hi.y, hi.z, hi.w};
        }

        // all waves done READING buf[cur] (b-frags in regs), then overwrite it with
        // batch t+2; those loads stay in flight across the next barrier (counted vmcnt)
        asm volatile("s_waitcnt lgkmcnt(0)" ::: "memory");
        __builtin_amdgcn_s_barrier();
        __builtin_amdgcn_sched_barrier(0);
        if (t < 6) {
            const int k0n = (t + 2) * 128;
            #pragma unroll
            for (int r = 0; r < 4; ++r)
                GLD_LDS(Bbase + (size_t)(r * 32) * FDIM + k0n, &Bs[cur + ldsRow + r * 32 * 128]);
            __builtin_amdgcn_sched_barrier(0);
        }

        __builtin_amdgcn_s_setprio(1);
        #pragma unroll
        for (int mt = 0; mt < 4; ++mt)
            #pragma unroll
            for (int nt = 0; nt < 4; ++nt)
                acc[mt][nt] = __builtin_amdgcn_mfma_scale_f32_16x16x128_f8f6f4(
                    a4[mt], b4[nt], acc[mt][nt], 0, 0, 0, 127, 0, 127);
        __builtin_amdgcn_s_setprio(0);
    }

    // peeled last K-step (t=7): buf1, full drain (nothing left to prefetch)
    asm volatile("s_waitcnt vmcnt(0)" ::: "memory");
    __builtin_amdgcn_s_barrier();
    __builtin_amdgcn_sched_barrier(0);
    {
        const int cur = 16384;
        const int k0  = 7 * 128;
        i32x8 a4[4], b4[4];
        #pragma unroll
        for (int mt = 0; mt < 4; ++mt) {
            const i32x4 lo = *(const i32x4*)(Afrag + (size_t)mt * 16 * FDIM + k0);
            const i32x4 hi = *(const i32x4*)(Afrag + (size_t)mt * 16 * FDIM + k0 + 16);
            a4[mt] = (i32x8){lo.x, lo.y, lo.z, lo.w, hi.x, hi.y, hi.z, hi.w};
        }
        #pragma unroll
        for (int nt = 0; nt < 4; ++nt) {
            const i32x4 lo = *(const i32x4*)&Bs[cur + fB + nt * 2048 + pg0];
            const i32x4 hi = *(const i32x4*)&Bs[cur + fB + nt * 2048 + pg1];
            b4[nt] = (i32x8){lo.x, lo.y, lo.z, lo.w, hi.x, hi.y, hi.z, hi.w};
        }
        __builtin_amdgcn_s_setprio(1);
        #pragma unroll
        for (int mt = 0; mt < 4; ++mt)
            #pragma unroll
            for (int nt = 0; nt < 4; ++nt)
                acc[mt][nt] = __builtin_amdgcn_mfma_scale_f32_16x16x128_f8f6f4(
                    a4[mt], b4[nt], acc[mt][nt], 0, 0, 0, 127, 0, 127);
        __builtin_amdgcn_s_setprio(0);
    }

    // epilogue: sim = acc/65536; d = sqrt(max(1-sim,0)); C/D: col=lane&15, row=(lane>>4)*4+reg
    const int row0 = bm * 128 + waveM;
    const int col0 = bn * 128 + waveN;
    #pragma unroll
    for (int mt = 0; mt < 4; ++mt) {
        #pragma unroll
        for (int r = 0; r < 4; ++r) {
            const int row = row0 + mt * 16 + (lane >> 4) * 4 + r;
            float part = 0.0f;
            #pragma unroll
            for (int nt = 0; nt < 4; ++nt) {
                const int col = col0 + nt * 16 + (lane & 15);
                const float sim = acc[mt][nt][r] * INV_SIM;
                const float dv = sqrtf(fmaxf(1.0f - sim, 0.0f));
                if (col < C_COLS) {
                    D[(size_t)row * C_COLS + col] = __float2bfloat16(dv);
                    part += dv;
                }
            }
            part += __shfl_xor(part, 1, 64);
            part += __shfl_xor(part, 2, 64);
            part += __shfl_xor(part, 4, 64);
            part += __shfl_xor(part, 8, 64);
            if ((lane & 15) == 0) atomicAdd(&rowsum[row], part);
        }
    }
}

// ---------------- finalize: out = (-|ds|/T) * (d + rowsum/1000) ----------------
__global__ __launch_bounds__(256) void finalize(
    const __hip_bfloat16* __restrict__ D, const float* __restrict__ rowsum,
    const float* __restrict__ scale, const float* __restrict__ temp,
    float* __restrict__ out)
{
    const size_t i = (size_t)blockIdx.x * 256 + threadIdx.x;   // 8-element group
    const float a = -fabsf(scale[0]) / temp[0];
    const int row = (int)((i * 8) / C_COLS);                   // 1000 % 8 == 0, no straddle
    const float m = rowsum[row] * (1.0f / (float)C_COLS);

    const bf16x8 dv = *(const bf16x8*)(D + i * 8);
    const __hip_bfloat16* dp = (const __hip_bfloat16*)&dv;
    float4 o0, o1;
    o0.x = a * (__bfloat162float(dp[0]) + m);
    o0.y = a * (__bfloat162float(dp[1]) + m);
    o0.z = a * (__bfloat162float(dp[2]) + m);
    o0.w = a * (__bfloat162float(dp[3]) + m);
    o1.x = a * (__bfloat162float(dp[4]) + m);
    o1.y = a * (__bfloat162float(dp[5]) + m);
    o1.z = a * (__bfloat162float(dp[6]) + m);
    o1.w = a * (__bfloat162float(dp[7]) + m);
    ((float4*)out)[i * 2]     = o0;
    ((float4*)out)[i * 2 + 1] = o1;
}

extern "C" void kernel_launch(void* const* d_in, const int* in_sizes, int n_in,
                              void* d_out, int out_size, void* d_ws, size_t ws_size,
                              hipStream_t stream)
{
    const float* features = (const float*)d_in[0];   // [16384,1024]
    const float* protos   = (const float*)d_in[1];   // [1000,1024]
    const float* dscale   = (const float*)d_in[2];   // [1]
    const float* temp     = (const float*)d_in[3];   // [1]
    float* out = (float*)d_out;                      // [16384,1000]

    char* ws = (char*)d_ws;
    unsigned char* fb = (unsigned char*)ws;                       // 16,777,216 B
    unsigned char* pb = (unsigned char*)(ws + 16777216);          //  1,048,576 B
    __hip_bfloat16* D = (__hip_bfloat16*)(ws + 17825792);         // 32,768,000 B
    float* rowsum     = (float*)(ws + 50593792);                  //     65,536 B

    normalize_all<<<FBLKS + C_PAD / 4, 256, 0, stream>>>(features, protos, fb, pb, rowsum);

    gemm_dist<<<1024, 256, 0, stream>>>(fb, pb, D, rowsum);

    finalize<<<(B_ROWS * C_COLS / 8) / 256, 256, 0, stream>>>(D, rowsum, dscale, temp, out);
}

// Round 9
// 160.000 us; speedup vs baseline: 1.4694x; 1.0927x over previous
//
#include <hip/hip_runtime.h>
#include <hip/hip_bf16.h>
#include <math.h>

#define B_ROWS 16384
#define C_COLS 1000
#define C_PAD  1024
#define FDIM   1024
#define FBLKS  4096           // feature normalize blocks (4 rows each)
#define FP8_SCALE 256.0f      // pre-scale before e4m3 quant (avoids subnormals)
#define INV_SIM   (1.0f / (FP8_SCALE * FP8_SCALE))

typedef __attribute__((ext_vector_type(8))) short bf16x8;
typedef __attribute__((ext_vector_type(4))) float f32x4;
typedef __attribute__((ext_vector_type(4))) int   i32x4;
typedef __attribute__((ext_vector_type(8))) int   i32x8;

// async global->LDS, 16B per lane; lds dst is wave-uniform base (HW puts lane i at base + i*16)
#define GLD_LDS(gp, lp) __builtin_amdgcn_global_load_lds( \
    (__attribute__((address_space(1))) void*)(gp),        \
    (__attribute__((address_space(3))) void*)(lp), 16, 0, 0)

// ---------------- fused row L2-normalize fp32 -> fp8 e4m3 (x256), one wave per row ---------
__global__ __launch_bounds__(256) void normalize_all(
    const float* __restrict__ feat, const float* __restrict__ prot,
    unsigned char* __restrict__ fb, unsigned char* __restrict__ pb,
    float* __restrict__ rowsum)
{
    const int lane = threadIdx.x & 63;
    const int wave = threadIdx.x >> 6;

    // fold rowsum zeroing into the first 64 blocks (replaces the memset dispatch)
    if (blockIdx.x < 64) rowsum[blockIdx.x * 256 + threadIdx.x] = 0.0f;

    const float* in;
    unsigned char* out;
    int row, nvalid;
    if (blockIdx.x < FBLKS) {
        row = blockIdx.x * 4 + wave;  in = feat; out = fb; nvalid = B_ROWS;
    } else {
        row = (blockIdx.x - FBLKS) * 4 + wave;  in = prot; out = pb; nvalid = C_COLS;
    }
    unsigned char* orow = out + (size_t)row * FDIM;

    if (row >= nvalid) {               // zero-pad prototype rows 1000..1023
        i32x4 z = {0, 0, 0, 0};
        ((i32x4*)orow)[lane] = z;      // 64 lanes x 16 B = 1024 B row
        return;
    }

    // lane owns 16 contiguous elements -> one 16 B fp8 store
    const float4* rp = (const float4*)(in + (size_t)row * FDIM);
    float4 v[4];
    float ss = 0.0f;
    #pragma unroll
    for (int c = 0; c < 4; ++c) {
        v[c] = rp[lane * 4 + c];
        ss += v[c].x * v[c].x + v[c].y * v[c].y + v[c].z * v[c].z + v[c].w * v[c].w;
    }
    #pragma unroll
    for (int off = 1; off < 64; off <<= 1) ss += __shfl_xor(ss, off, 64);
    const float inv = FP8_SCALE / sqrtf(fmaxf(ss, 1e-24f));

    i32x4 pk;
    #pragma unroll
    for (int c = 0; c < 4; ++c) {
        int w0 = __builtin_amdgcn_cvt_pk_fp8_f32(v[c].x * inv, v[c].y * inv, 0, false);
        w0     = __builtin_amdgcn_cvt_pk_fp8_f32(v[c].z * inv, v[c].w * inv, w0, true);
        pk[c] = w0;
    }
    ((i32x4*)orow)[lane] = pk;
}

// ---------------- MX-fp8 GEMM 128x128, BK=128, counted-vmcnt depth-2 pipeline (r6 core) ---
// r9 change vs r6: fragment loads write DIRECTLY into the i32x8 halves
// (((i32x4*)&frag)[0/1] = ds_read) instead of element-wise vector construction --
// removes up to 128 v_mov_b32 per K-step (VALUBusy was 2x MfmaUtil in every profile).
// Everything else identical to the proven r6 schedule.
__global__ __launch_bounds__(256) void gemm_dist(
    const unsigned char* __restrict__ A,
    const unsigned char* __restrict__ Bp,
    __hip_bfloat16* __restrict__ D,
    float* __restrict__ rowsum)
{
    __shared__ unsigned char As[2 * 128 * 128];   // 32 KB (double-buffered)
    __shared__ unsigned char Bs[2 * 128 * 128];   // 32 KB

    const int tid  = threadIdx.x;
    const int lane = tid & 63;
    const int wave = tid >> 6;

    // XCD swizzle: the 8 bn-blocks of one bm share id%8 (same XCD) for A-tile L2 reuse
    const int id  = blockIdx.x;             // 0..1023
    const int xcd = id & 7;
    const int seq = id >> 3;                // 0..127
    const int bn  = seq & 7;                // 0..7
    const int bm  = xcd * 16 + (seq >> 3);  // 0..127

    const int waveM = (wave >> 1) * 64;
    const int waveN = (wave & 1) * 64;

    f32x4 acc[4][4] = {};

    // staging: round r covers rows [r*32, r*32+32); wave w -> rows r*32+w*8 .. +8
    // lane i -> row +(i>>3), phys granule i&7, fetching logical granule (i&7)^(i>>3)
    const int srow8 = lane >> 3;
    const int sg    = (lane & 7) ^ srow8;
    const unsigned char* Abase = A  + ((size_t)(bm * 128 + wave * 8 + srow8)) * FDIM + sg * 16;
    const unsigned char* Bbase = Bp + ((size_t)(bn * 128 + wave * 8 + srow8)) * FDIM + sg * 16;

    // frag addressing: R = waveX + mt*16 + (lane&15); R&7 = lane&7.
    // logical granules for this lane: 2q, 2q+1 (q = lane>>4); phys = g ^ (lane&7)
    const int q2   = (lane >> 4) * 2;
    const int bxor = lane & 7;
    const int fA = (waveM + (lane & 15)) * 128;
    const int fB = (waveN + (lane & 15)) * 128;
    const int pg0 = ((q2)     ^ bxor) * 16;
    const int pg1 = ((q2 + 1) ^ bxor) * 16;

    const int ldsRow = wave * 8 * 128;      // this wave's staging base within a tile

    // prologue: batch0 -> buf0, batch1 -> buf1 (issue order = vmcnt retirement order)
    #pragma unroll
    for (int r = 0; r < 4; ++r) {
        GLD_LDS(Abase + (size_t)(r * 32) * FDIM, &As[ldsRow + r * 32 * 128]);
        GLD_LDS(Bbase + (size_t)(r * 32) * FDIM, &Bs[ldsRow + r * 32 * 128]);
    }
    __builtin_amdgcn_sched_barrier(0);
    #pragma unroll
    for (int r = 0; r < 4; ++r) {
        GLD_LDS(Abase + (size_t)(r * 32) * FDIM + 128, &As[16384 + ldsRow + r * 32 * 128]);
        GLD_LDS(Bbase + (size_t)(r * 32) * FDIM + 128, &Bs[16384 + ldsRow + r * 32 * 128]);
    }
    __builtin_amdgcn_sched_barrier(0);

    #pragma unroll 1
    for (int t = 0; t < 7; ++t) {
        // own batch-t retired (8 newest = later batches still in flight), then
        // barrier => ALL waves' batch-t slices landed in buf[t&1]
        asm volatile("s_waitcnt vmcnt(8)" ::: "memory");
        __builtin_amdgcn_s_barrier();
        __builtin_amdgcn_sched_barrier(0);

        const int cur = (t & 1) << 14;      // byte offset of current buffer (0 / 16384)

        // frag reads: 16 x ds_read_b128 straight into the i32x8 halves (no v_mov repack)
        i32x8 a4[4], b4[4];
        #pragma unroll
        for (int nt = 0; nt < 4; ++nt) {
            ((i32x4*)&b4[nt])[0] = *(const i32x4*)&Bs[cur + fB + nt * 2048 + pg0];
            ((i32x4*)&b4[nt])[1] = *(const i32x4*)&Bs[cur + fB + nt * 2048 + pg1];
        }
        #pragma unroll
        for (int mt = 0; mt < 4; ++mt) {
            ((i32x4*)&a4[mt])[0] = *(const i32x4*)&As[cur + fA + mt * 2048 + pg0];
            ((i32x4*)&a4[mt])[1] = *(const i32x4*)&As[cur + fA + mt * 2048 + pg1];
        }

        // MFMA cluster (compiler inserts fine-grained lgkm waits for the frag loads)
        __builtin_amdgcn_s_setprio(1);
        #pragma unroll
        for (int mt = 0; mt < 4; ++mt)
            #pragma unroll
            for (int nt = 0; nt < 4; ++nt)
                acc[mt][nt] = __builtin_amdgcn_mfma_scale_f32_16x16x128_f8f6f4(
                    a4[mt], b4[nt], acc[mt][nt], 0, 0, 0, 127, 0, 127);
        __builtin_amdgcn_s_setprio(0);

        if (t < 6) {
            // all waves done READING buf[cur] (lgkm drained; MFMAs consumed the regs),
            // then overwrite buf[cur] with batch t+2. Loads stay in flight across the
            // next iteration's barrier (counted vmcnt -- the T4 point).
            asm volatile("s_waitcnt lgkmcnt(0)" ::: "memory");
            __builtin_amdgcn_s_barrier();
            __builtin_amdgcn_sched_barrier(0);
            const int k0n = (t + 2) * 128;
            #pragma unroll
            for (int r = 0; r < 4; ++r) {
                GLD_LDS(Abase + (size_t)(r * 32) * FDIM + k0n, &As[cur + ldsRow + r * 32 * 128]);
                GLD_LDS(Bbase + (size_t)(r * 32) * FDIM + k0n, &Bs[cur + ldsRow + r * 32 * 128]);
            }
            __builtin_amdgcn_sched_barrier(0);
        }
    }

    // peeled last K-step (t=7): buf1, full drain (nothing left to prefetch)
    asm volatile("s_waitcnt vmcnt(0)" ::: "memory");
    __builtin_amdgcn_s_barrier();
    __builtin_amdgcn_sched_barrier(0);
    {
        const int cur = 16384;
        i32x8 a4[4], b4[4];
        #pragma unroll
        for (int nt = 0; nt < 4; ++nt) {
            ((i32x4*)&b4[nt])[0] = *(const i32x4*)&Bs[cur + fB + nt * 2048 + pg0];
            ((i32x4*)&b4[nt])[1] = *(const i32x4*)&Bs[cur + fB + nt * 2048 + pg1];
        }
        #pragma unroll
        for (int mt = 0; mt < 4; ++mt) {
            ((i32x4*)&a4[mt])[0] = *(const i32x4*)&As[cur + fA + mt * 2048 + pg0];
            ((i32x4*)&a4[mt])[1] = *(const i32x4*)&As[cur + fA + mt * 2048 + pg1];
        }
        __builtin_amdgcn_s_setprio(1);
        #pragma unroll
        for (int mt = 0; mt < 4; ++mt)
            #pragma unroll
            for (int nt = 0; nt < 4; ++nt)
                acc[mt][nt] = __builtin_amdgcn_mfma_scale_f32_16x16x128_f8f6f4(
                    a4[mt], b4[nt], acc[mt][nt], 0, 0, 0, 127, 0, 127);
        __builtin_amdgcn_s_setprio(0);
    }

    // epilogue: sim = acc/65536; d = sqrt(max(1-sim,0)); C/D: col=lane&15, row=(lane>>4)*4+reg
    const int row0 = bm * 128 + waveM;
    const int col0 = bn * 128 + waveN;
    #pragma unroll
    for (int mt = 0; mt < 4; ++mt) {
        #pragma unroll
        for (int r = 0; r < 4; ++r) {
            const int row = row0 + mt * 16 + (lane >> 4) * 4 + r;
            float part = 0.0f;
            #pragma unroll
            for (int nt = 0; nt < 4; ++nt) {
                const int col = col0 + nt * 16 + (lane & 15);
                const float sim = acc[mt][nt][r] * INV_SIM;
                const float dv = sqrtf(fmaxf(1.0f - sim, 0.0f));
                if (col < C_COLS) {
                    D[(size_t)row * C_COLS + col] = __float2bfloat16(dv);
                    part += dv;
                }
            }
            part += __shfl_xor(part, 1, 64);
            part += __shfl_xor(part, 2, 64);
            part += __shfl_xor(part, 4, 64);
            part += __shfl_xor(part, 8, 64);
            if ((lane & 15) == 0) atomicAdd(&rowsum[row], part);
        }
    }
}

// ---------------- finalize: out = (-|ds|/T) * (d + rowsum/1000) ----------------
__global__ __launch_bounds__(256) void finalize(
    const __hip_bfloat16* __restrict__ D, const float* __restrict__ rowsum,
    const float* __restrict__ scale, const float* __restrict__ temp,
    float* __restrict__ out)
{
    const size_t i = (size_t)blockIdx.x * 256 + threadIdx.x;   // 8-element group
    const float a = -fabsf(scale[0]) / temp[0];
    const int row = (int)((i * 8) / C_COLS);                   // 1000 % 8 == 0, no straddle
    const float m = rowsum[row] * (1.0f / (float)C_COLS);

    const bf16x8 dv = *(const bf16x8*)(D + i * 8);
    const __hip_bfloat16* dp = (const __hip_bfloat16*)&dv;
    float4 o0, o1;
    o0.x = a * (__bfloat162float(dp[0]) + m);
    o0.y = a * (__bfloat162float(dp[1]) + m);
    o0.z = a * (__bfloat162float(dp[2]) + m);
    o0.w = a * (__bfloat162float(dp[3]) + m);
    o1.x = a * (__bfloat162float(dp[4]) + m);
    o1.y = a * (__bfloat162float(dp[5]) + m);
    o1.z = a * (__bfloat162float(dp[6]) + m);
    o1.w = a * (__bfloat162float(dp[7]) + m);
    ((float4*)out)[i * 2]     = o0;
    ((float4*)out)[i * 2 + 1] = o1;
}

extern "C" void kernel_launch(void* const* d_in, const int* in_sizes, int n_in,
                              void* d_out, int out_size, void* d_ws, size_t ws_size,
                              hipStream_t stream)
{
    const float* features = (const float*)d_in[0];   // [16384,1024]
    const float* protos   = (const float*)d_in[1];   // [1000,1024]
    const float* dscale   = (const float*)d_in[2];   // [1]
    const float* temp     = (const float*)d_in[3];   // [1]
    float* out = (float*)d_out;                      // [16384,1000]

    char* ws = (char*)d_ws;
    unsigned char* fb = (unsigned char*)ws;                       // 16,777,216 B
    unsigned char* pb = (unsigned char*)(ws + 16777216);          //  1,048,576 B
    __hip_bfloat16* D = (__hip_bfloat16*)(ws + 17825792);         // 32,768,000 B
    float* rowsum     = (float*)(ws + 50593792);                  //     65,536 B

    normalize_all<<<FBLKS + C_PAD / 4, 256, 0, stream>>>(features, protos, fb, pb, rowsum);

    gemm_dist<<<1024, 256, 0, stream>>>(fb, pb, D, rowsum);

    finalize<<<(B_ROWS * C_COLS / 8) / 256, 256, 0, stream>>>(D, rowsum, dscale, temp, out);
}

// Round 10
// 159.949 us; speedup vs baseline: 1.4698x; 1.0003x over previous
//
#include <hip/hip_runtime.h>
#include <hip/hip_bf16.h>
#include <math.h>

#define B_ROWS 16384
#define C_COLS 1000
#define C_PAD  1024
#define FDIM   1024
#define FBLKS  4096           // feature normalize blocks (4 rows each)
#define FP8_SCALE 256.0f      // pre-scale before e4m3 quant (avoids subnormals)
#define INV_SIM   (1.0f / (FP8_SCALE * FP8_SCALE))

typedef __attribute__((ext_vector_type(8))) short bf16x8;
typedef __attribute__((ext_vector_type(4))) float f32x4;
typedef __attribute__((ext_vector_type(4))) int   i32x4;
typedef __attribute__((ext_vector_type(8))) int   i32x8;

// async global->LDS, 16B per lane; lds dst is wave-uniform base (HW puts lane i at base + i*16)
#define GLD_LDS(gp, lp) __builtin_amdgcn_global_load_lds( \
    (__attribute__((address_space(1))) void*)(gp),        \
    (__attribute__((address_space(3))) void*)(lp), 16, 0, 0)

// ---------------- fused row L2-normalize fp32 -> fp8 e4m3 (x256), one wave per row ---------
__global__ __launch_bounds__(256) void normalize_all(
    const float* __restrict__ feat, const float* __restrict__ prot,
    unsigned char* __restrict__ fb, unsigned char* __restrict__ pb,
    float* __restrict__ rowsum)
{
    const int lane = threadIdx.x & 63;
    const int wave = threadIdx.x >> 6;

    // fold rowsum zeroing into the first 64 blocks (replaces the memset dispatch)
    if (blockIdx.x < 64) rowsum[blockIdx.x * 256 + threadIdx.x] = 0.0f;

    const float* in;
    unsigned char* out;
    int row, nvalid;
    if (blockIdx.x < FBLKS) {
        row = blockIdx.x * 4 + wave;  in = feat; out = fb; nvalid = B_ROWS;
    } else {
        row = (blockIdx.x - FBLKS) * 4 + wave;  in = prot; out = pb; nvalid = C_COLS;
    }
    unsigned char* orow = out + (size_t)row * FDIM;

    if (row >= nvalid) {               // zero-pad prototype rows 1000..1023
        i32x4 z = {0, 0, 0, 0};
        ((i32x4*)orow)[lane] = z;      // 64 lanes x 16 B = 1024 B row
        return;
    }

    // lane owns 16 contiguous elements -> one 16 B fp8 store
    const float4* rp = (const float4*)(in + (size_t)row * FDIM);
    float4 v[4];
    float ss = 0.0f;
    #pragma unroll
    for (int c = 0; c < 4; ++c) {
        v[c] = rp[lane * 4 + c];
        ss += v[c].x * v[c].x + v[c].y * v[c].y + v[c].z * v[c].z + v[c].w * v[c].w;
    }
    #pragma unroll
    for (int off = 1; off < 64; off <<= 1) ss += __shfl_xor(ss, off, 64);
    const float inv = FP8_SCALE / sqrtf(fmaxf(ss, 1e-24f));

    i32x4 pk;
    #pragma unroll
    for (int c = 0; c < 4; ++c) {
        int w0 = __builtin_amdgcn_cvt_pk_fp8_f32(v[c].x * inv, v[c].y * inv, 0, false);
        w0     = __builtin_amdgcn_cvt_pk_fp8_f32(v[c].z * inv, v[c].w * inv, w0, true);
        pk[c] = w0;
    }
    ((i32x4*)orow)[lane] = pk;
}

// ---------------- MX-fp8 GEMM 256x256, BK=128, counted-vmcnt depth-2 (r6 schedule scaled) -
// vs r9/128^2: staged bytes halve (134 vs 268 MB), GLDs halve, each barrier pair covers
// 2x FLOPs (32 MFMA/wave/K-step). Same proven schedule: per-wave batch = 8 GLDs ->
// vmcnt(8) depth-2, lgkmcnt(0)+barrier before overwrite. 512 thr / 8 waves (2M x 4N),
// acc[8][4], A-frags read in two mt-halves to cap regs ~240. 128 KB dynamic LDS ->
// 1 block/CU (2 waves/SIMD). Grid 64x4 = 256 = exactly 1/CU. XCD swizzle: the 4 bn of
// one bm share id%8. LDS granule swizzle (g ^ (row&7)) unchanged -> 2-way free.
__global__ __launch_bounds__(512, 2) void gemm_dist(
    const unsigned char* __restrict__ A,
    const unsigned char* __restrict__ Bp,
    __hip_bfloat16* __restrict__ D,
    float* __restrict__ rowsum)
{
    extern __shared__ unsigned char LDS[];        // 131072 B: A dbuf [0,64K), B dbuf [64K,128K)
    unsigned char* As = LDS;                      // + buf*32768
    unsigned char* Bs = LDS + 65536;

    const int tid  = threadIdx.x;                 // 0..511
    const int lane = tid & 63;
    const int wave = tid >> 6;                    // 0..7

    // XCD swizzle: 256 blocks, 8 XCDs; the 4 bn-blocks of one bm share xcd
    const int id  = blockIdx.x;             // 0..255
    const int xcd = id & 7;
    const int seq = id >> 3;                // 0..31
    const int bn  = seq & 3;                // 0..3
    const int bm  = xcd * 8 + (seq >> 2);   // 0..63

    const int waveM = (wave >> 2) * 128;    // 0 / 128
    const int waveN = (wave & 3) * 64;      // 0..192

    f32x4 acc[8][4] = {};

    // staging: wave w owns rows [w*32, w*32+32) of both tiles; round r -> rows w*32+r*8..+8
    // lane i -> row +(i>>3), phys granule i&7, fetching logical granule (i&7)^(i>>3)
    const int srow8 = lane >> 3;
    const int sg    = (lane & 7) ^ srow8;
    const unsigned char* Abase = A  + ((size_t)(bm * 256 + wave * 32 + srow8)) * FDIM + sg * 16;
    const unsigned char* Bbase = Bp + ((size_t)(bn * 256 + wave * 32 + srow8)) * FDIM + sg * 16;
    const int ldsW = wave * 4096;           // wave's 32-row strip (32*128 B) within a tile

    // frag addressing: R = waveX + mt*16 + (lane&15); R&7 = lane&7.
    // logical granules for this lane: 2q, 2q+1 (q = lane>>4); phys = g ^ (lane&7)
    const int q2   = (lane >> 4) * 2;
    const int bxor = lane & 7;
    const int fA = (waveM + (lane & 15)) * 128;
    const int fB = (waveN + (lane & 15)) * 128;
    const int pg0 = ((q2)     ^ bxor) * 16;
    const int pg1 = ((q2 + 1) ^ bxor) * 16;

    // batch issue: 4 A-rounds + 4 B-rounds = 8 GLDs/wave (vmcnt unit, same count as r6)
#define STAGE_BATCH(K0_, BUF_) do {                                                  \
        _Pragma("unroll")                                                            \
        for (int r_ = 0; r_ < 4; ++r_)                                               \
            GLD_LDS(Abase + (size_t)(r_ * 8) * FDIM + (K0_), &As[(BUF_) + ldsW + r_ * 1024]); \
        _Pragma("unroll")                                                            \
        for (int r_ = 0; r_ < 4; ++r_)                                               \
            GLD_LDS(Bbase + (size_t)(r_ * 8) * FDIM + (K0_), &Bs[(BUF_) + ldsW + r_ * 1024]); \
    } while (0)

#define COMPUTE_STEP(CUR_) do {                                                      \
        i32x8 b4[4], a4[4];                                                          \
        _Pragma("unroll")                                                            \
        for (int nt = 0; nt < 4; ++nt) {                                             \
            ((i32x4*)&b4[nt])[0] = *(const i32x4*)&Bs[(CUR_) + fB + nt * 2048 + pg0];\
            ((i32x4*)&b4[nt])[1] = *(const i32x4*)&Bs[(CUR_) + fB + nt * 2048 + pg1];\
        }                                                                            \
        _Pragma("unroll")                                                            \
        for (int mt = 0; mt < 4; ++mt) {                                             \
            ((i32x4*)&a4[mt])[0] = *(const i32x4*)&As[(CUR_) + fA + mt * 2048 + pg0];\
            ((i32x4*)&a4[mt])[1] = *(const i32x4*)&As[(CUR_) + fA + mt * 2048 + pg1];\
        }                                                                            \
        __builtin_amdgcn_s_setprio(1);                                               \
        _Pragma("unroll")                                                            \
        for (int mt = 0; mt < 4; ++mt)                                               \
            _Pragma("unroll")                                                        \
            for (int nt = 0; nt < 4; ++nt)                                           \
                acc[mt][nt] = __builtin_amdgcn_mfma_scale_f32_16x16x128_f8f6f4(      \
                    a4[mt], b4[nt], acc[mt][nt], 0, 0, 0, 127, 0, 127);              \
        __builtin_amdgcn_s_setprio(0);                                               \
        _Pragma("unroll")                                                            \
        for (int mt = 0; mt < 4; ++mt) {                                             \
            ((i32x4*)&a4[mt])[0] = *(const i32x4*)&As[(CUR_) + fA + (mt + 4) * 2048 + pg0]; \
            ((i32x4*)&a4[mt])[1] = *(const i32x4*)&As[(CUR_) + fA + (mt + 4) * 2048 + pg1]; \
        }                                                                            \
        __builtin_amdgcn_s_setprio(1);                                               \
        _Pragma("unroll")                                                            \
        for (int mt = 0; mt < 4; ++mt)                                               \
            _Pragma("unroll")                                                        \
            for (int nt = 0; nt < 4; ++nt)                                           \
                acc[mt + 4][nt] = __builtin_amdgcn_mfma_scale_f32_16x16x128_f8f6f4(  \
                    a4[mt], b4[nt], acc[mt + 4][nt], 0, 0, 0, 127, 0, 127);          \
        __builtin_amdgcn_s_setprio(0);                                               \
    } while (0)

    // prologue: batch0 -> buf0, batch1 -> buf1 (issue order = vmcnt retirement order)
    STAGE_BATCH(0, 0);
    __builtin_amdgcn_sched_barrier(0);
    STAGE_BATCH(128, 32768);
    __builtin_amdgcn_sched_barrier(0);

    #pragma unroll 1
    for (int t = 0; t < 7; ++t) {
        // own batch-t retired (8 newest = later batches in flight), then barrier =>
        // ALL waves' batch-t slices landed in buf[t&1]
        asm volatile("s_waitcnt vmcnt(8)" ::: "memory");
        __builtin_amdgcn_s_barrier();
        __builtin_amdgcn_sched_barrier(0);

        const int cur = (t & 1) << 15;      // byte offset of current buffer (0 / 32768)

        COMPUTE_STEP(cur);

        // all waves done READING buf[cur], then overwrite it with batch t+2; those
        // loads stay in flight across the next barrier (counted vmcnt -- T4)
        asm volatile("s_waitcnt lgkmcnt(0)" ::: "memory");
        __builtin_amdgcn_s_barrier();
        __builtin_amdgcn_sched_barrier(0);
        if (t < 6) {
            const int k0n = (t + 2) * 128;
            STAGE_BATCH(k0n, cur);
            __builtin_amdgcn_sched_barrier(0);
        }
    }

    // peeled last K-step (t=7): buf1, full drain (nothing left to prefetch)
    asm volatile("s_waitcnt vmcnt(0)" ::: "memory");
    __builtin_amdgcn_s_barrier();
    __builtin_amdgcn_sched_barrier(0);
    COMPUTE_STEP(32768);

    // epilogue: sim = acc/65536; d = sqrt(max(1-sim,0)); C/D: col=lane&15, row=(lane>>4)*4+reg
    const int row0 = bm * 256 + waveM;
    const int col0 = bn * 256 + waveN;
    #pragma unroll
    for (int mt = 0; mt < 8; ++mt) {
        #pragma unroll
        for (int r = 0; r < 4; ++r) {
            const int row = row0 + mt * 16 + (lane >> 4) * 4 + r;
            float part = 0.0f;
            #pragma unroll
            for (int nt = 0; nt < 4; ++nt) {
                const int col = col0 + nt * 16 + (lane & 15);
                const float sim = acc[mt][nt][r] * INV_SIM;
                const float dv = sqrtf(fmaxf(1.0f - sim, 0.0f));
                if (col < C_COLS) {
                    D[(size_t)row * C_COLS + col] = __float2bfloat16(dv);
                    part += dv;
                }
            }
            part += __shfl_xor(part, 1, 64);
            part += __shfl_xor(part, 2, 64);
            part += __shfl_xor(part, 4, 64);
            part += __shfl_xor(part, 8, 64);
            if ((lane & 15) == 0) atomicAdd(&rowsum[row], part);
        }
    }
}

// ---------------- finalize: out = (-|ds|/T) * (d + rowsum/1000) ----------------
__global__ __launch_bounds__(256) void finalize(
    const __hip_bfloat16* __restrict__ D, const float* __restrict__ rowsum,
    const float* __restrict__ scale, const float* __restrict__ temp,
    float* __restrict__ out)
{
    const size_t i = (size_t)blockIdx.x * 256 + threadIdx.x;   // 8-element group
    const float a = -fabsf(scale[0]) / temp[0];
    const int row = (int)((i * 8) / C_COLS);                   // 1000 % 8 == 0, no straddle
    const float m = rowsum[row] * (1.0f / (float)C_COLS);

    const bf16x8 dv = *(const bf16x8*)(D + i * 8);
    const __hip_bfloat16* dp = (const __hip_bfloat16*)&dv;
    float4 o0, o1;
    o0.x = a * (__bfloat162float(dp[0]) + m);
    o0.y = a * (__bfloat162float(dp[1]) + m);
    o0.z = a * (__bfloat162float(dp[2]) + m);
    o0.w = a * (__bfloat162float(dp[3]) + m);
    o1.x = a * (__bfloat162float(dp[4]) + m);
    o1.y = a * (__bfloat162float(dp[5]) + m);
    o1.z = a * (__bfloat162float(dp[6]) + m);
    o1.w = a * (__bfloat162float(dp[7]) + m);
    ((float4*)out)[i * 2]     = o0;
    ((float4*)out)[i * 2 + 1] = o1;
}

extern "C" void kernel_launch(void* const* d_in, const int* in_sizes, int n_in,
                              void* d_out, int out_size, void* d_ws, size_t ws_size,
                              hipStream_t stream)
{
    const float* features = (const float*)d_in[0];   // [16384,1024]
    const float* protos   = (const float*)d_in[1];   // [1000,1024]
    const float* dscale   = (const float*)d_in[2];   // [1]
    const float* temp     = (const float*)d_in[3];   // [1]
    float* out = (float*)d_out;                      // [16384,1000]

    char* ws = (char*)d_ws;
    unsigned char* fb = (unsigned char*)ws;                       // 16,777,216 B
    unsigned char* pb = (unsigned char*)(ws + 16777216);          //  1,048,576 B
    __hip_bfloat16* D = (__hip_bfloat16*)(ws + 17825792);         // 32,768,000 B
    float* rowsum     = (float*)(ws + 50593792);                  //     65,536 B

    // one-time: allow 128 KB dynamic LDS for the 256^2 tile (host-side, capture-safe)
    static int lds_ok = 0;
    if (!lds_ok) {
        (void)hipFuncSetAttribute(reinterpret_cast<const void*>(gemm_dist),
                                  hipFuncAttributeMaxDynamicSharedMemorySize, 131072);
        lds_ok = 1;
    }

    normalize_all<<<FBLKS + C_PAD / 4, 256, 0, stream>>>(features, protos, fb, pb, rowsum);

    gemm_dist<<<256, 512, 131072, stream>>>(fb, pb, D, rowsum);

    finalize<<<(B_ROWS * C_COLS / 8) / 256, 256, 0, stream>>>(D, rowsum, dscale, temp, out);
}